// Round 1
// baseline (1488.868 us; speedup 1.0000x reference)
//
#include <hip/hip_runtime.h>
#include <hip/hip_bf16.h>

typedef __attribute__((ext_vector_type(8))) short short8;
typedef __attribute__((ext_vector_type(4))) float floatx4;

#define DD 256

__device__ __forceinline__ unsigned short f2bf(float f) {
    unsigned int u = __builtin_bit_cast(unsigned int, f);
    u += 0x7FFFu + ((u >> 16) & 1u);   // round-to-nearest-even
    return (unsigned short)(u >> 16);
}

__device__ __forceinline__ float sigm(float x) { return 1.0f / (1.0f + __expf(-x)); }
__device__ __forceinline__ float tanh_fast(float x) { return 2.0f / (1.0f + __expf(-2.0f * x)) - 1.0f; }

// ---------------- pack weights to bf16, transposed [N][K] ----------------
__global__ void pack_weights(const float* __restrict__ W_f, const float* __restrict__ W_g,
                             unsigned short* __restrict__ WfT, unsigned short* __restrict__ WgT) {
    int idx = blockIdx.x * 256 + threadIdx.x;
    if (idx < 65536) {
        int n = idx >> 8, k = idx & 255;
        WfT[idx] = f2bf(W_f[k * 256 + n]);          // WfT[n][k]
    } else {
        int i2 = idx - 65536;                        // 0..196607
        int n = i2 >> 8, k = i2 & 255;
        WgT[i2] = f2bf(W_g[k * 768 + n]);            // WgT[n][k], n<768
    }
}

// ---------------- CSR offsets from sorted segment_ids ----------------
__global__ void build_start(const int* __restrict__ seg, int E, int P, int* __restrict__ start) {
    int e = blockIdx.x * blockDim.x + threadIdx.x;
    if (e >= E) return;
    int s = seg[e];
    if (e == 0) {
        for (int p = 0; p <= s; ++p) start[p] = 0;
    } else {
        int sp = seg[e - 1];
        for (int p = sp + 1; p <= s; ++p) start[p] = e;
    }
    if (e == E - 1) {
        for (int p = s + 1; p <= P; ++p) start[p] = E;
    }
}

// ---------------- hs_sum: one wave per parent, zero atomics ----------------
__global__ void hs_reduce(const float* __restrict__ child_hs, const int* __restrict__ start,
                          int P, float* __restrict__ hs_sum) {
    int wave = threadIdx.x >> 6, lane = threadIdx.x & 63;
    int p = blockIdx.x * 4 + wave;
    if (p >= P) return;
    int lo = start[p], hi = start[p + 1];
    float4 acc = make_float4(0.f, 0.f, 0.f, 0.f);
    const float4* src = (const float4*)child_hs;
    for (int e = lo; e < hi; ++e) {
        float4 v = src[(size_t)e * 64 + lane];
        acc.x += v.x; acc.y += v.y; acc.z += v.z; acc.w += v.w;
    }
    ((float4*)hs_sum)[(size_t)p * 64 + lane] = acc;
}

// ---------------- GEMM1: F = sigmoid(child_hs @ W_f + b_f); fc += F * child_cs ----------------
// block = 256 thr = 4 waves; M_block = 64 (wave w: rows w*16..+16), N = 256 (16 tiles), K = 256 (8 ksteps)
__global__ __launch_bounds__(256, 2) void gemm1_fc(
    const float* __restrict__ child_hs, const float* __restrict__ child_cs,
    const int* __restrict__ seg, const unsigned short* __restrict__ WfT,
    const float* __restrict__ b_f, float* __restrict__ fc, int E) {
    __shared__ __align__(16) unsigned short ldsB[8192];   // 16 KB: one 32x256 bf16 k-slice, frag-packed
    const int tid = threadIdx.x;
    const int w = tid >> 6, lane = tid & 63;
    const int nl = lane & 15, q = lane >> 4;
    const int e_base = blockIdx.x * 64 + w * 16;

    floatx4 acc[16];
#pragma unroll
    for (int t = 0; t < 16; ++t) acc[t] = (floatx4){0.f, 0.f, 0.f, 0.f};

    const float* Arow = child_hs + (size_t)(e_base + nl) * DD;   // A-frag row m = lane&15

    for (int ks = 0; ks < 8; ++ks) {
        // stage W_f^T k-slice into LDS, packed so frag read = contiguous 16B per lane
#pragma unroll
        for (int r = 0; r < 4; ++r) {
            int chunk = tid + r * 256;                 // 1024 chunks = 256 n-rows x 4 q
            int n = chunk >> 2, qb = chunk & 3;
            uint4 v = *(const uint4*)(WfT + n * 256 + ks * 32 + qb * 8);
            int dst = ((n >> 4) << 6) + (qb << 4) + (n & 15);   // [tile][q][nl]
            ((uint4*)ldsB)[dst] = v;
        }
        // A fragment: 8 consecutive k at k = ks*32 + q*8
        float4 a0 = *(const float4*)(Arow + ks * 32 + q * 8);
        float4 a1 = *(const float4*)(Arow + ks * 32 + q * 8 + 4);
        short8 af;
        af[0] = (short)f2bf(a0.x); af[1] = (short)f2bf(a0.y);
        af[2] = (short)f2bf(a0.z); af[3] = (short)f2bf(a0.w);
        af[4] = (short)f2bf(a1.x); af[5] = (short)f2bf(a1.y);
        af[6] = (short)f2bf(a1.z); af[7] = (short)f2bf(a1.w);
        __syncthreads();
#pragma unroll
        for (int t = 0; t < 16; ++t) {
            short8 bf = ((const short8*)ldsB)[t * 64 + lane];
            acc[t] = __builtin_amdgcn_mfma_f32_16x16x32_bf16(af, bf, acc[t], 0, 0, 0);
        }
        __syncthreads();
    }

    // epilogue: C/D layout col = lane&15 (within tile), row = q*4 + reg
    int e0 = e_base + q * 4;
    int s0 = seg[e0], s1 = seg[e0 + 1], s2 = seg[e0 + 2], s3 = seg[e0 + 3];
#pragma unroll
    for (int t = 0; t < 16; ++t) {
        int n = t * 16 + nl;
        float bias = b_f[n];
        float v0 = sigm(acc[t][0] + bias) * child_cs[(size_t)(e0 + 0) * DD + n];
        float v1 = sigm(acc[t][1] + bias) * child_cs[(size_t)(e0 + 1) * DD + n];
        float v2 = sigm(acc[t][2] + bias) * child_cs[(size_t)(e0 + 2) * DD + n];
        float v3 = sigm(acc[t][3] + bias) * child_cs[(size_t)(e0 + 3) * DD + n];
        // run-combine consecutive equal segments (sorted) -> fewer atomics
        float a = v0; int s = s0;
        if (s1 == s) { a += v1; } else { atomicAdd(&fc[(size_t)s * DD + n], a); a = v1; s = s1; }
        if (s2 == s) { a += v2; } else { atomicAdd(&fc[(size_t)s * DD + n], a); a = v2; s = s2; }
        if (s3 == s) { a += v3; } else { atomicAdd(&fc[(size_t)s * DD + n], a); a = v3; s = s3; }
        atomicAdd(&fc[(size_t)s * DD + n], a);
    }
}

// ---------------- GEMM2: gates = hs_sum @ W_gates + b; fused LSTM epilogue ----------------
// block = 256 thr = 4 waves; M_block = 16 rows (shared), wave w owns col-groups cg = 4w..4w+3,
// each cg = 16 output cols with its i (cg), o (16+cg), g (32+cg) tiles -> 12 acc tiles/wave.
__global__ __launch_bounds__(256, 2) void gemm2_lstm(
    const float* __restrict__ hs_sum, const unsigned short* __restrict__ WgT,
    const float* __restrict__ b_g, float* __restrict__ h_out, float* __restrict__ c_out, int P) {
    const int tid = threadIdx.x;
    const int w = tid >> 6, lane = tid & 63;
    const int nl = lane & 15, q = lane >> 4;
    const int p_base = blockIdx.x * 16;
    const int cg0 = w * 4;

    floatx4 acc[12];
#pragma unroll
    for (int t = 0; t < 12; ++t) acc[t] = (floatx4){0.f, 0.f, 0.f, 0.f};

    const float* Arow = hs_sum + (size_t)(p_base + nl) * DD;

    for (int ks = 0; ks < 8; ++ks) {
        float4 a0 = *(const float4*)(Arow + ks * 32 + q * 8);
        float4 a1 = *(const float4*)(Arow + ks * 32 + q * 8 + 4);
        short8 af;
        af[0] = (short)f2bf(a0.x); af[1] = (short)f2bf(a0.y);
        af[2] = (short)f2bf(a0.z); af[3] = (short)f2bf(a0.w);
        af[4] = (short)f2bf(a1.x); af[5] = (short)f2bf(a1.y);
        af[6] = (short)f2bf(a1.z); af[7] = (short)f2bf(a1.w);
#pragma unroll
        for (int cgl = 0; cgl < 4; ++cgl) {
            int cg = cg0 + cgl;
#pragma unroll
            for (int part = 0; part < 3; ++part) {
                int nrow = part * 256 + cg * 16 + nl;    // col in [0,768)
                short8 bf = *(const short8*)(WgT + nrow * 256 + ks * 32 + q * 8);
                acc[cgl * 3 + part] =
                    __builtin_amdgcn_mfma_f32_16x16x32_bf16(af, bf, acc[cgl * 3 + part], 0, 0, 0);
            }
        }
    }

    __syncthreads();   // all waves done reading hs_sum rows before h overwrites them

#pragma unroll
    for (int cgl = 0; cgl < 4; ++cgl) {
        int n = (cg0 + cgl) * 16 + nl;
        float bi = b_g[n], bo = b_g[256 + n], bg = b_g[512 + n];
#pragma unroll
        for (int reg = 0; reg < 4; ++reg) {
            int p = p_base + q * 4 + reg;
            float I = acc[cgl * 3 + 0][reg] + bi;
            float O = acc[cgl * 3 + 1][reg] + bo;
            float G = acc[cgl * 3 + 2][reg] + bg;
            float iv = sigm(I), ov = sigm(O), gv = tanh_fast(G);
            float c = iv * gv + c_out[(size_t)p * DD + n];   // c_out currently holds fc
            float hv = ov * tanh_fast(c);
            h_out[(size_t)p * DD + n] = hv;
            c_out[(size_t)p * DD + n] = c;
        }
    }
}

extern "C" void kernel_launch(void* const* d_in, const int* in_sizes, int n_in,
                              void* d_out, int out_size, void* d_ws, size_t ws_size,
                              hipStream_t stream) {
    const float* child_hs = (const float*)d_in[0];
    const float* child_cs = (const float*)d_in[1];
    const int*   seg      = (const int*)d_in[2];
    // d_in[3] = num_segments (device scalar) — P derived from out_size instead
    const float* W_gates  = (const float*)d_in[4];
    const float* b_gates  = (const float*)d_in[5];
    const float* W_f      = (const float*)d_in[6];
    const float* b_f      = (const float*)d_in[7];

    const int D = 256;
    const int E = in_sizes[0] / D;
    const int P = out_size / (2 * D);

    float* h_out = (float*)d_out;                         // doubles as hs_sum accumulator
    float* c_out = (float*)d_out + (size_t)P * D;         // doubles as fc accumulator

    unsigned short* WfT = (unsigned short*)d_ws;          // 65536 bf16
    unsigned short* WgT = WfT + 65536;                    // 196608 bf16
    int* start = (int*)(WgT + 196608);                    // P+1 ints

    // fc accumulator must start at zero (harness poisons d_out)
    hipMemsetAsync(c_out, 0, (size_t)P * D * sizeof(float), stream);

    pack_weights<<<1024, 256, 0, stream>>>(W_f, W_gates, WfT, WgT);
    build_start<<<(E + 255) / 256, 256, 0, stream>>>(seg, E, P, start);
    hs_reduce<<<(P + 3) / 4, 256, 0, stream>>>(child_hs, start, P, h_out);
    gemm1_fc<<<E / 64, 256, 0, stream>>>(child_hs, child_cs, seg, WfT, b_f, c_out, E);
    gemm2_lstm<<<P / 16, 256, 0, stream>>>(h_out, WgT, b_gates, h_out, c_out, P);
}